// Round 1
// baseline (2862.260 us; speedup 1.0000x reference)
//
#include <hip/hip_runtime.h>
#include <hip/hip_bf16.h>
#include <math.h>

#define B_ 2
#define L_ 2048
#define D_ 2048
#define H_ 32
#define HKV_ 8
#define HD_ 64
#define EPS_ 1e-5f

// ---------------------------------------------------------------------------
// Tiled fp32 GEMM block: C[row0:+128, col0:+128] = A[row0:+128, :K] @ W[:K, col0:+128]
// 256 threads, 8x8 micro-tile per thread, BK=16.
// ---------------------------------------------------------------------------
__device__ __forceinline__ void gemm_tile(
    const float* __restrict__ A, const float* __restrict__ W,
    float* __restrict__ C, int K, int N, int row0, int col0)
{
  __shared__ float As[16][132];  // transposed A tile: As[k][m]; stride 132 words = 528B (16B aligned)
  __shared__ float Bs[16][132];  // Bs[k][n]
  const int t  = threadIdx.x;
  const int tx = t & 15, ty = t >> 4;

  float acc[8][8];
#pragma unroll
  for (int i = 0; i < 8; i++)
#pragma unroll
    for (int j = 0; j < 8; j++) acc[i][j] = 0.f;

  for (int k0 = 0; k0 < K; k0 += 16) {
    // A tile: 128 rows x 16 cols, float4 loads, transposed scatter into As
#pragma unroll
    for (int i = 0; i < 2; i++) {
      int r = (t >> 2) + i * 64;   // 0..127
      int c = (t & 3) * 4;         // 0,4,8,12
      float4 a4 = *(const float4*)&A[(size_t)(row0 + r) * K + k0 + c];
      As[c + 0][r] = a4.x; As[c + 1][r] = a4.y;
      As[c + 2][r] = a4.z; As[c + 3][r] = a4.w;
    }
    // B tile: 16 rows x 128 cols, float4 load + float4 LDS store
#pragma unroll
    for (int i = 0; i < 2; i++) {
      int r = (t >> 5) + i * 8;    // 0..15
      int c = (t & 31) * 4;        // 0..124
      *(float4*)&Bs[r][c] = *(const float4*)&W[(size_t)(k0 + r) * N + col0 + c];
    }
    __syncthreads();

#pragma unroll
    for (int k = 0; k < 16; k++) {
      float a[8], b[8];
#pragma unroll
      for (int i = 0; i < 8; i++) a[i] = As[k][ty * 8 + i];
#pragma unroll
      for (int j = 0; j < 8; j++) b[j] = Bs[k][tx * 8 + j];
#pragma unroll
      for (int i = 0; i < 8; i++)
#pragma unroll
        for (int j = 0; j < 8; j++) acc[i][j] += a[i] * b[j];
    }
    __syncthreads();
  }

#pragma unroll
  for (int i = 0; i < 8; i++) {
    float* Cp = C + (size_t)(row0 + ty * 8 + i) * N + col0 + tx * 8;
#pragma unroll
    for (int j = 0; j < 8; j++) Cp[j] = acc[i][j];
  }
}

// Fused QKV projection: blockIdx.x selects which weight/output segment.
// gridDim = (24, 32): 16 blocks for Wq cols, 4 for Wk, 4 for Wv.
__global__ __launch_bounds__(256) void qkv_gemm(
    const float* __restrict__ x,
    const float* __restrict__ Wq, const float* __restrict__ Wk,
    const float* __restrict__ Wv,
    float* __restrict__ q_raw, float* __restrict__ k_raw, float* __restrict__ v_raw)
{
  int bx = blockIdx.x;
  const float* W; float* C; int N; int col0;
  if (bx < 16)      { W = Wq; C = q_raw; N = H_ * HD_;   col0 = bx * 128; }
  else if (bx < 20) { W = Wk; C = k_raw; N = HKV_ * HD_; col0 = (bx - 16) * 128; }
  else              { W = Wv; C = v_raw; N = HKV_ * HD_; col0 = (bx - 20) * 128; }
  gemm_tile(x, W, C, D_, N, blockIdx.y * 128, col0);
}

__global__ __launch_bounds__(256) void out_gemm(
    const float* __restrict__ attn, const float* __restrict__ Wo,
    float* __restrict__ out)
{
  gemm_tile(attn, Wo, out, H_ * HD_, D_, blockIdx.y * 128, blockIdx.x * 128);
}

// ---------------------------------------------------------------------------
// In-place per-head RMS norm + RoPE. One wave per (token, head).
// buf layout: [B*L][nheads*64] token-major.
// ---------------------------------------------------------------------------
__global__ __launch_bounds__(256) void norm_rope_kernel(
    float* __restrict__ buf, const float* __restrict__ w, int nheads, int lognh)
{
  int gid  = blockIdx.x * 256 + threadIdx.x;
  int wave = gid >> 6;
  int lane = threadIdx.x & 63;
  if (wave >= B_ * L_ * nheads) return;
  int head  = wave & (nheads - 1);
  int token = wave >> lognh;
  int l     = token & (L_ - 1);

  size_t idx = (size_t)token * (nheads * HD_) + head * HD_ + lane;
  float x = buf[idx];

  // RMS over the 64-lane head
  float ss = x * x;
#pragma unroll
  for (int off = 32; off; off >>= 1) ss += __shfl_xor(ss, off);
  float xn = x * rsqrtf(ss * (1.0f / HD_) + EPS_) * w[lane];

  // RoPE: pair (i, i+32)
  float partner = __shfl_xor(xn, 32);
  int   fi = lane & 31;
  float inv_freq = powf(1.0e6f, -(float)(2 * fi) * (1.0f / HD_));
  float ang = (float)l * inv_freq;
  float c = cosf(ang), s = sinf(ang);
  buf[idx] = (lane < 32) ? (xn * c - partner * s) : (xn * c + partner * s);
}

// ---------------------------------------------------------------------------
// Causal GQA flash attention, fp32. BQ=32 q-rows per block, BK=64 k-rows/tile.
// 256 threads: thread = (q-row r = t>>3, col-group c8 = t&7).
// Q/K/V read token-major; output written token-major [B*L][H*64].
// ---------------------------------------------------------------------------
#define BQ 32
#define BKT 64

__global__ __launch_bounds__(256) void flash_kernel(
    const float* __restrict__ Q, const float* __restrict__ K,
    const float* __restrict__ V, float* __restrict__ Oa)
{
  __shared__ float Qs[BQ][HD_ + 4];   // stride 68 words = 272B (16B aligned)
  __shared__ float Ks[BKT][HD_ + 4];
  __shared__ float Vs[BKT][HD_ + 4];
  __shared__ float Ps[BQ][BKT + 8];   // stride 72

  const int t  = threadIdx.x;
  const int r  = t >> 3;       // 0..31 q row in tile
  const int c8 = t & 7;        // 0..7
  const int qb = blockIdx.x, h = blockIdx.y, b = blockIdx.z;
  const int kvh = h >> 2;      // g = H/HKV = 4
  const int q0 = qb * BQ;
  const float scale = 0.125f;  // 64^-0.5

  const float* Qp = Q + (size_t)(b * L_ + q0) * (H_ * HD_) + h * HD_;
  const float* Kp = K + (size_t)(b * L_) * (HKV_ * HD_) + kvh * HD_;
  const float* Vp = V + (size_t)(b * L_) * (HKV_ * HD_) + kvh * HD_;

  // Q tile (scale folded in): 32x64 floats
#pragma unroll
  for (int i = 0; i < 2; i++) {
    int rr = (t >> 4) + i * 16;
    int cc = (t & 15) * 4;
    float4 v4 = *(const float4*)&Qp[(size_t)rr * (H_ * HD_) + cc];
    v4.x *= scale; v4.y *= scale; v4.z *= scale; v4.w *= scale;
    *(float4*)&Qs[rr][cc] = v4;
  }

  float m = -INFINITY, lsum = 0.f;
  float o[8];
#pragma unroll
  for (int j = 0; j < 8; j++) o[j] = 0.f;

  const int ntiles = (q0 + BQ - 1) / BKT + 1;
  for (int kt = 0; kt < ntiles; kt++) {
    const int kk0 = kt * BKT;
    __syncthreads();   // protects Qs (first iter) and Ks/Vs/Ps reuse (later iters)
#pragma unroll
    for (int i = 0; i < 4; i++) {
      int rr = (t >> 4) + i * 16;
      int cc = (t & 15) * 4;
      *(float4*)&Ks[rr][cc] = *(const float4*)&Kp[(size_t)(kk0 + rr) * (HKV_ * HD_) + cc];
      *(float4*)&Vs[rr][cc] = *(const float4*)&Vp[(size_t)(kk0 + rr) * (HKV_ * HD_) + cc];
    }
    __syncthreads();

    // S = Q K^T for this thread's 8 k-columns (kk = j*8 + c8)
    float s[8];
#pragma unroll
    for (int j = 0; j < 8; j++) s[j] = 0.f;
#pragma unroll
    for (int d0 = 0; d0 < HD_; d0 += 16) {
      float qv[16];
#pragma unroll
      for (int dd = 0; dd < 16; dd++) qv[dd] = Qs[r][d0 + dd];
#pragma unroll
      for (int j = 0; j < 8; j++) {
        int kk = j * 8 + c8;
#pragma unroll
        for (int dd = 0; dd < 16; dd++) s[j] += qv[dd] * Ks[kk][d0 + dd];
      }
    }
    const int qg = q0 + r;
#pragma unroll
    for (int j = 0; j < 8; j++) {
      int kglob = kk0 + j * 8 + c8;
      if (kglob > qg) s[j] = -INFINITY;
    }

    // online softmax: row max over 8 local + 8 lanes sharing the row
    float mloc = s[0];
#pragma unroll
    for (int j = 1; j < 8; j++) mloc = fmaxf(mloc, s[j]);
#pragma unroll
    for (int off = 4; off; off >>= 1) mloc = fmaxf(mloc, __shfl_xor(mloc, off));
    float mnew = fmaxf(m, mloc);

    float p[8], lloc = 0.f;
#pragma unroll
    for (int j = 0; j < 8; j++) { p[j] = __expf(s[j] - mnew); lloc += p[j]; }
#pragma unroll
    for (int off = 4; off; off >>= 1) lloc += __shfl_xor(lloc, off);

    float alpha = __expf(m - mnew);   // first tile: exp(-inf) = 0
    lsum = lsum * alpha + lloc;
    m = mnew;
#pragma unroll
    for (int j = 0; j < 8; j++) o[j] *= alpha;

#pragma unroll
    for (int j = 0; j < 8; j++) Ps[r][j * 8 + c8] = p[j];
    __syncthreads();

    // O += P V  (this thread owns output cols c8*8 .. c8*8+7)
#pragma unroll
    for (int kk = 0; kk < BKT; kk++) {
      float pv = Ps[r][kk];
#pragma unroll
      for (int j = 0; j < 8; j++) o[j] += pv * Vs[kk][c8 * 8 + j];
    }
  }

  float inv = 1.0f / lsum;
  float* Op = Oa + (size_t)(b * L_ + q0 + r) * (H_ * HD_) + h * HD_ + c8 * 8;
#pragma unroll
  for (int j = 0; j < 8; j++) Op[j] = o[j] * inv;
}

// ---------------------------------------------------------------------------
extern "C" void kernel_launch(void* const* d_in, const int* in_sizes, int n_in,
                              void* d_out, int out_size, void* d_ws, size_t ws_size,
                              hipStream_t stream)
{
  const float* x  = (const float*)d_in[0];
  const float* Wq = (const float*)d_in[1];
  const float* Wk = (const float*)d_in[2];
  const float* Wv = (const float*)d_in[3];
  const float* Wo = (const float*)d_in[4];
  const float* qw = (const float*)d_in[5];
  const float* kw = (const float*)d_in[6];
  float* out = (float*)d_out;

  float* ws    = (float*)d_ws;
  float* q_raw = ws;                                  // [4096][2048]
  float* k_raw = q_raw + (size_t)(B_ * L_) * (H_ * HD_);   // [4096][512]
  float* v_raw = k_raw + (size_t)(B_ * L_) * (HKV_ * HD_); // [4096][512]
  float* attn  = v_raw + (size_t)(B_ * L_) * (HKV_ * HD_); // [4096][2048]

  // 1) QKV projections (fused launch)
  qkv_gemm<<<dim3(24, 32), 256, 0, stream>>>(x, Wq, Wk, Wv, q_raw, k_raw, v_raw);

  // 2) RMS norm + RoPE, in place (token-major layouts)
  norm_rope_kernel<<<(B_ * L_ * H_) / 4, 256, 0, stream>>>(q_raw, qw, H_, 5);
  norm_rope_kernel<<<(B_ * L_ * HKV_) / 4, 256, 0, stream>>>(k_raw, kw, HKV_, 3);

  // 3) causal GQA flash attention
  flash_kernel<<<dim3(L_ / BQ, H_, B_), 256, 0, stream>>>(q_raw, k_raw, v_raw, attn);

  // 4) output projection
  out_gemm<<<dim3(D_ / 128, (B_ * L_) / 128), 256, 0, stream>>>(attn, Wo, out);
}

// Round 2
// 1337.407 us; speedup vs baseline: 2.1402x; 2.1402x over previous
//
#include <hip/hip_runtime.h>
#include <hip/hip_bf16.h>
#include <math.h>

#define B_ 2
#define L_ 2048
#define D_ 2048
#define H_ 32
#define HKV_ 8
#define HD_ 64
#define EPS_ 1e-5f

typedef __attribute__((ext_vector_type(8))) short short8_t;
typedef __attribute__((ext_vector_type(4))) short short4_t;
typedef __attribute__((ext_vector_type(4))) float float4_t;

__device__ __forceinline__ ushort f2bf(float f) {
  union { float f; unsigned u; } v; v.f = f;
  unsigned r = v.u + 0x7fff + ((v.u >> 16) & 1);   // RNE
  return (ushort)(r >> 16);
}

// ---------------------------------------------------------------------------
// fp32 GEMM (unchanged this round): C[row0:+128,col0:+128] = A @ W
// ---------------------------------------------------------------------------
__device__ __forceinline__ void gemm_tile(
    const float* __restrict__ A, const float* __restrict__ W,
    float* __restrict__ C, int K, int N, int row0, int col0)
{
  __shared__ float As[16][132];
  __shared__ float Bs[16][132];
  const int t  = threadIdx.x;
  const int tx = t & 15, ty = t >> 4;

  float acc[8][8];
#pragma unroll
  for (int i = 0; i < 8; i++)
#pragma unroll
    for (int j = 0; j < 8; j++) acc[i][j] = 0.f;

  for (int k0 = 0; k0 < K; k0 += 16) {
#pragma unroll
    for (int i = 0; i < 2; i++) {
      int r = (t >> 2) + i * 64;
      int c = (t & 3) * 4;
      float4 a4 = *(const float4*)&A[(size_t)(row0 + r) * K + k0 + c];
      As[c + 0][r] = a4.x; As[c + 1][r] = a4.y;
      As[c + 2][r] = a4.z; As[c + 3][r] = a4.w;
    }
#pragma unroll
    for (int i = 0; i < 2; i++) {
      int r = (t >> 5) + i * 8;
      int c = (t & 31) * 4;
      *(float4*)&Bs[r][c] = *(const float4*)&W[(size_t)(k0 + r) * N + col0 + c];
    }
    __syncthreads();
#pragma unroll
    for (int k = 0; k < 16; k++) {
      float a[8], b[8];
#pragma unroll
      for (int i = 0; i < 8; i++) a[i] = As[k][ty * 8 + i];
#pragma unroll
      for (int j = 0; j < 8; j++) b[j] = Bs[k][tx * 8 + j];
#pragma unroll
      for (int i = 0; i < 8; i++)
#pragma unroll
        for (int j = 0; j < 8; j++) acc[i][j] += a[i] * b[j];
    }
    __syncthreads();
  }
#pragma unroll
  for (int i = 0; i < 8; i++) {
    float* Cp = C + (size_t)(row0 + ty * 8 + i) * N + col0 + tx * 8;
#pragma unroll
    for (int j = 0; j < 8; j++) Cp[j] = acc[i][j];
  }
}

__global__ __launch_bounds__(256) void qkv_gemm(
    const float* __restrict__ x,
    const float* __restrict__ Wq, const float* __restrict__ Wk,
    const float* __restrict__ Wv,
    float* __restrict__ q_raw, float* __restrict__ k_raw, float* __restrict__ v_raw)
{
  int bx = blockIdx.x;
  const float* W; float* C; int N; int col0;
  if (bx < 16)      { W = Wq; C = q_raw; N = H_ * HD_;   col0 = bx * 128; }
  else if (bx < 20) { W = Wk; C = k_raw; N = HKV_ * HD_; col0 = (bx - 16) * 128; }
  else              { W = Wv; C = v_raw; N = HKV_ * HD_; col0 = (bx - 20) * 128; }
  gemm_tile(x, W, C, D_, N, blockIdx.y * 128, col0);
}

__global__ __launch_bounds__(256) void out_gemm(
    const float* __restrict__ attn, const float* __restrict__ Wo,
    float* __restrict__ out)
{
  gemm_tile(attn, Wo, out, H_ * HD_, D_, blockIdx.y * 128, blockIdx.x * 128);
}

// ---------------------------------------------------------------------------
// RMS norm + RoPE; reads fp32, writes bf16 (scale folded for Q).
// One wave per (token, head).
// ---------------------------------------------------------------------------
__global__ __launch_bounds__(256) void norm_rope_bf(
    const float* __restrict__ in, const float* __restrict__ w,
    ushort* __restrict__ outb, int nheads, int lognh, float oscale)
{
  int gid  = blockIdx.x * 256 + threadIdx.x;
  int wave = gid >> 6;
  int lane = threadIdx.x & 63;
  int head  = wave & (nheads - 1);
  int token = wave >> lognh;
  int l     = token & (L_ - 1);

  size_t idx = (size_t)token * (nheads * HD_) + head * HD_ + lane;
  float x = in[idx];

  float ss = x * x;
#pragma unroll
  for (int off = 32; off; off >>= 1) ss += __shfl_xor(ss, off);
  float xn = x * rsqrtf(ss * (1.0f / HD_) + EPS_) * w[lane];

  float partner = __shfl_xor(xn, 32);
  int   fi = lane & 31;
  float inv_freq = powf(1.0e6f, -(float)(2 * fi) * (1.0f / HD_));
  float ang = (float)l * inv_freq;
  float cv = cosf(ang), sv = sinf(ang);
  float res = (lane < 32) ? (xn * cv - partner * sv) : (xn * cv + partner * sv);
  outb[idx] = f2bf(res * oscale);
}

// ---------------------------------------------------------------------------
// V: fp32 token-major [b*L][HKV*64] -> bf16 transposed Vt[(b*8+kvh)*64+d][2048]
// with per-64-token-tile column permutation k' = (k&15)*4 + (k>>4)
// (matches the MFMA C-layout pack of P so P-writes are contiguous b64).
// ---------------------------------------------------------------------------
__global__ __launch_bounds__(256) void transpose_v(
    const float* __restrict__ v_raw, ushort* __restrict__ vt)
{
  int t   = threadIdx.x;
  int kk0 = blockIdx.x * 64, kvh = blockIdx.y, b = blockIdx.z;
  int d = t >> 2, uu = t & 3;
  const float* src = v_raw + (size_t)(b * L_) * (HKV_ * HD_) + kvh * HD_ + d;
  ushort* dst = vt + ((size_t)((b * HKV_ + kvh) * HD_ + d)) * L_ + kk0 + uu * 16;
  ushort vals[16];
#pragma unroll
  for (int u = 0; u < 16; u++) {
    int kp = uu * 16 + u;                    // permuted index within tile
    int ko = (kp & 3) * 16 + (kp >> 2);      // original token index
    vals[u] = f2bf(src[(size_t)(kk0 + ko) * (HKV_ * HD_)]);
  }
#pragma unroll
  for (int u = 0; u < 16; u += 4)
    *(short4_t*)&dst[u] = *(short4_t*)&vals[u];
}

// ---------------------------------------------------------------------------
// MFMA flash attention. BQ = BK = 64, 256 threads = 4 waves.
// Wave w owns q rows [w*16, w*16+16). mfma_f32_16x16x32_bf16.
// A-frag: m = lane&15, k = quad*8+j.  B-frag: n = lane&15, k = quad*8+j.
// C/D  : col = lane&15, row = quad*4 + reg.
// ---------------------------------------------------------------------------
__global__ __launch_bounds__(256) void flash_mfma(
    const ushort* __restrict__ Qb, const ushort* __restrict__ Kb,
    const ushort* __restrict__ Vt, float* __restrict__ Oa)
{
  __shared__ short Ks[64][72];   // [token-in-tile][d]        stride 144B
  __shared__ short Vs[64][72];   // [d][k' permuted]          stride 144B
  __shared__ short Ps[64][72];   // [q row][k' permuted]      stride 144B

  const int t    = threadIdx.x;
  const int w    = t >> 6;
  const int lane = t & 63;
  const int quad = lane >> 4;
  const int c    = lane & 15;
  const int qb = blockIdx.x, h = blockIdx.y, b = blockIdx.z;
  const int kvh = h >> 2;
  const int q0  = qb * 64;

  // Q fragments: held in registers for the whole block (scale pre-folded)
  const ushort* qp = Qb + ((size_t)(b * L_ + q0 + w * 16 + c)) * (H_ * HD_) + h * HD_;
  short8_t qf0 = *(const short8_t*)&qp[quad * 8];
  short8_t qf1 = *(const short8_t*)&qp[32 + quad * 8];

  float4_t o[4];
#pragma unroll
  for (int i = 0; i < 4; i++) o[i] = (float4_t){0.f, 0.f, 0.f, 0.f};
  float mm[4], ll[4];
#pragma unroll
  for (int r = 0; r < 4; r++) { mm[r] = -__builtin_inff(); ll[r] = 0.f; }

  const ushort* kbase = Kb + (size_t)(b * L_) * (HKV_ * HD_) + kvh * HD_;
  const ushort* vbase = Vt + (size_t)((b * HKV_ + kvh) * HD_) * L_;

  const int sr = t >> 2, su = t & 3;   // staging: row, 32B-chunk

  for (int kt = 0; kt <= qb; kt++) {
    const int kk0 = kt * 64;
    __syncthreads();
    {
      const ushort* ksrc = kbase + (size_t)(kk0 + sr) * (HKV_ * HD_) + su * 16;
      *(short8_t*)&Ks[sr][su * 16]     = *(const short8_t*)&ksrc[0];
      *(short8_t*)&Ks[sr][su * 16 + 8] = *(const short8_t*)&ksrc[8];
      const ushort* vsrc = vbase + (size_t)sr * L_ + kk0 + su * 16;
      *(short8_t*)&Vs[sr][su * 16]     = *(const short8_t*)&vsrc[0];
      *(short8_t*)&Vs[sr][su * 16 + 8] = *(const short8_t*)&vsrc[8];
    }
    __syncthreads();

    // S = Q K^T : 4 col-tiles of 16, K-dim 64 = 2 mfma each
    float4_t S[4];
#pragma unroll
    for (int tt = 0; tt < 4; tt++) {
      short8_t kf0 = *(const short8_t*)&Ks[tt * 16 + c][quad * 8];
      short8_t kf1 = *(const short8_t*)&Ks[tt * 16 + c][32 + quad * 8];
      float4_t s = (float4_t){0.f, 0.f, 0.f, 0.f};
      s = __builtin_amdgcn_mfma_f32_16x16x32_bf16(qf0, kf0, s, 0, 0, 0);
      s = __builtin_amdgcn_mfma_f32_16x16x32_bf16(qf1, kf1, s, 0, 0, 0);
      S[tt] = s;
    }

    // causal mask: only the diagonal tile needs it
    if (kt == qb) {
#pragma unroll
      for (int tt = 0; tt < 4; tt++)
#pragma unroll
        for (int r = 0; r < 4; r++) {
          int kg = kk0 + tt * 16 + c;
          int qg = q0 + w * 16 + quad * 4 + r;
          if (kg > qg) S[tt][r] = -__builtin_inff();
        }
    }

    // online softmax per row (row = quad*4 + r; cols spread over 16 lanes + 4 tiles)
#pragma unroll
    for (int r = 0; r < 4; r++) {
      float mloc = fmaxf(fmaxf(S[0][r], S[1][r]), fmaxf(S[2][r], S[3][r]));
      mloc = fmaxf(mloc, __shfl_xor(mloc, 1));
      mloc = fmaxf(mloc, __shfl_xor(mloc, 2));
      mloc = fmaxf(mloc, __shfl_xor(mloc, 4));
      mloc = fmaxf(mloc, __shfl_xor(mloc, 8));
      float mnew = fmaxf(mm[r], mloc);
      float al = __expf(mm[r] - mnew);
      float p0 = __expf(S[0][r] - mnew);
      float p1 = __expf(S[1][r] - mnew);
      float p2 = __expf(S[2][r] - mnew);
      float p3 = __expf(S[3][r] - mnew);
      float ls = p0 + p1 + p2 + p3;
      ls += __shfl_xor(ls, 1);
      ls += __shfl_xor(ls, 2);
      ls += __shfl_xor(ls, 4);
      ls += __shfl_xor(ls, 8);
      ll[r] = ll[r] * al + ls;
      mm[r] = mnew;
#pragma unroll
      for (int tt = 0; tt < 4; tt++) o[tt][r] *= al;
      // P write: permuted col' = c*4 + tt -> contiguous b64
      ushort pk[4] = { f2bf(p0), f2bf(p1), f2bf(p2), f2bf(p3) };
      *(short4_t*)&Ps[w * 16 + quad * 4 + r][c * 4] = *(short4_t*)&pk[0];
    }

    // O += P V   (P in A-layout from own rows; Vt rows are contiguous in k')
    short8_t pf0 = *(const short8_t*)&Ps[w * 16 + c][quad * 8];
    short8_t pf1 = *(const short8_t*)&Ps[w * 16 + c][32 + quad * 8];
#pragma unroll
    for (int tt = 0; tt < 4; tt++) {
      short8_t vf0 = *(const short8_t*)&Vs[tt * 16 + c][quad * 8];
      short8_t vf1 = *(const short8_t*)&Vs[tt * 16 + c][32 + quad * 8];
      o[tt] = __builtin_amdgcn_mfma_f32_16x16x32_bf16(pf0, vf0, o[tt], 0, 0, 0);
      o[tt] = __builtin_amdgcn_mfma_f32_16x16x32_bf16(pf1, vf1, o[tt], 0, 0, 0);
    }
  }

  float* op = Oa + ((size_t)(b * L_ + q0 + w * 16 + quad * 4)) * (H_ * HD_) + h * HD_ + c;
#pragma unroll
  for (int r = 0; r < 4; r++) {
    float inv = 1.0f / ll[r];
#pragma unroll
    for (int tt = 0; tt < 4; tt++)
      op[(size_t)r * (H_ * HD_) + tt * 16] = o[tt][r] * inv;
  }
}

// ---------------------------------------------------------------------------
extern "C" void kernel_launch(void* const* d_in, const int* in_sizes, int n_in,
                              void* d_out, int out_size, void* d_ws, size_t ws_size,
                              hipStream_t stream)
{
  const float* x  = (const float*)d_in[0];
  const float* Wq = (const float*)d_in[1];
  const float* Wk = (const float*)d_in[2];
  const float* Wv = (const float*)d_in[3];
  const float* Wo = (const float*)d_in[4];
  const float* qw = (const float*)d_in[5];
  const float* kw = (const float*)d_in[6];
  float* out = (float*)d_out;

  const size_t QN = (size_t)B_ * L_ * H_ * HD_;    // 8M
  const size_t KN = (size_t)B_ * L_ * HKV_ * HD_;  // 2M

  float* ws    = (float*)d_ws;
  float* q_raw = ws;                    // 8M fp32 (reused as attn output)
  float* k_raw = q_raw + QN;            // 2M fp32
  float* v_raw = k_raw + KN;            // 2M fp32
  ushort* q_bf = (ushort*)(v_raw + KN); // 8M bf16
  ushort* k_bf = q_bf + QN;             // 2M bf16
  ushort* vt   = k_bf + KN;             // 2M bf16
  float* attn  = q_raw;                 // alias: q_raw dead after norm_rope

  // 1) QKV projections (fp32)
  qkv_gemm<<<dim3(24, 32), 256, 0, stream>>>(x, Wq, Wk, Wv, q_raw, k_raw, v_raw);

  // 2) RMS norm + RoPE -> bf16 (Q gets softmax scale folded)
  norm_rope_bf<<<(B_ * L_ * H_) / 4, 256, 0, stream>>>(q_raw, qw, q_bf, H_, 5, 0.125f);
  norm_rope_bf<<<(B_ * L_ * HKV_) / 4, 256, 0, stream>>>(k_raw, kw, k_bf, HKV_, 3, 1.0f);

  // 3) V -> bf16 transposed+permuted
  transpose_v<<<dim3(L_ / 64, HKV_, B_), 256, 0, stream>>>(v_raw, vt);

  // 4) MFMA flash attention
  flash_mfma<<<dim3(L_ / 64, H_, B_), 256, 0, stream>>>(q_bf, k_bf, vt, attn);

  // 5) output projection (fp32)
  out_gemm<<<dim3(D_ / 128, (B_ * L_) / 128), 256, 0, stream>>>(attn, Wo, out);
}

// Round 3
// 505.689 us; speedup vs baseline: 5.6601x; 2.6447x over previous
//
#include <hip/hip_runtime.h>
#include <math.h>

#define B_ 2
#define L_ 2048
#define D_ 2048
#define H_ 32
#define HKV_ 8
#define HD_ 64
#define EPS_ 1e-5f

typedef _Float16 half_t;
typedef __attribute__((ext_vector_type(8))) _Float16 half8_t;
typedef __attribute__((ext_vector_type(4))) _Float16 half4_t;
typedef __attribute__((ext_vector_type(4))) float float4_t;

// ---------------------------------------------------------------------------
// fp32 -> fp16 straight convert (8 elems/thread)
// ---------------------------------------------------------------------------
__global__ __launch_bounds__(256) void convert_f32_f16(
    const float* __restrict__ in, half_t* __restrict__ out)
{
  size_t i = ((size_t)blockIdx.x * 256 + threadIdx.x) * 8;
  float4 v0 = *(const float4*)&in[i];
  float4 v1 = *(const float4*)&in[i + 4];
  half8_t h;
  h[0] = (half_t)v0.x; h[1] = (half_t)v0.y; h[2] = (half_t)v0.z; h[3] = (half_t)v0.w;
  h[4] = (half_t)v1.x; h[5] = (half_t)v1.y; h[6] = (half_t)v1.z; h[7] = (half_t)v1.w;
  *(half8_t*)&out[i] = h;
}

// ---------------------------------------------------------------------------
// W[K][N] fp32 -> Wt[N][K] fp16 (32x32 LDS tile transpose)
// ---------------------------------------------------------------------------
__global__ __launch_bounds__(256) void transpose_convert(
    const float* __restrict__ W, half_t* __restrict__ Wt, int N, int K)
{
  __shared__ float tile[32][33];
  int k0 = blockIdx.x * 32, n0 = blockIdx.y * 32;
  int tx = threadIdx.x & 31, ty = threadIdx.x >> 5;   // ty 0..7
#pragma unroll
  for (int i = 0; i < 4; i++)
    tile[ty + i * 8][tx] = W[(size_t)(k0 + ty + i * 8) * N + n0 + tx];
  __syncthreads();
#pragma unroll
  for (int i = 0; i < 4; i++)
    Wt[(size_t)(n0 + ty + i * 8) * K + k0 + tx] = (half_t)tile[tx][ty + i * 8];
}

// ---------------------------------------------------------------------------
// fp16 MFMA GEMM: C[row0:+128][col0:+128] = A[M][K] @ Bt[N][K]^T
// 256 thr = 4 waves (2x2), each wave 64x64 via 4x4 mfma_f32_16x16x32_f16.
// LDS rows padded to 40 halves (80B = 20-bank stride, conflict-free).
// ---------------------------------------------------------------------------
template <typename CT>
__device__ __forceinline__ void gemm_tile_f16(
    const half_t* __restrict__ A, const half_t* __restrict__ Bt,
    CT* __restrict__ C, int K, int ldc, int row0, int col0)
{
  __shared__ half_t As[128][40];
  __shared__ half_t Bs[128][40];
  const int t    = threadIdx.x;
  const int lane = t & 63;
  const int w    = t >> 6;
  const int quad = lane >> 4, c = lane & 15;
  const int wm = (w >> 1) * 64, wn = (w & 1) * 64;

  float4_t acc[4][4];
#pragma unroll
  for (int i = 0; i < 4; i++)
#pragma unroll
    for (int j = 0; j < 4; j++) acc[i][j] = (float4_t){0.f, 0.f, 0.f, 0.f};

  const int sr = t >> 1;            // 0..127
  const int sc = (t & 1) * 16;      // 0 or 16 halves
  const half_t* Ap = A  + (size_t)(row0 + sr) * K + sc;
  const half_t* Bp = Bt + (size_t)(col0 + sr) * K + sc;

  for (int k0 = 0; k0 < K; k0 += 32) {
    half8_t a0 = *(const half8_t*)&Ap[k0];
    half8_t a1 = *(const half8_t*)&Ap[k0 + 8];
    half8_t b0 = *(const half8_t*)&Bp[k0];
    half8_t b1 = *(const half8_t*)&Bp[k0 + 8];
    __syncthreads();
    *(half8_t*)&As[sr][sc]     = a0;
    *(half8_t*)&As[sr][sc + 8] = a1;
    *(half8_t*)&Bs[sr][sc]     = b0;
    *(half8_t*)&Bs[sr][sc + 8] = b1;
    __syncthreads();

    half8_t af[4], bf[4];
#pragma unroll
    for (int i = 0; i < 4; i++) af[i] = *(const half8_t*)&As[wm + i * 16 + c][quad * 8];
#pragma unroll
    for (int j = 0; j < 4; j++) bf[j] = *(const half8_t*)&Bs[wn + j * 16 + c][quad * 8];
#pragma unroll
    for (int i = 0; i < 4; i++)
#pragma unroll
      for (int j = 0; j < 4; j++)
        acc[i][j] = __builtin_amdgcn_mfma_f32_16x16x32_f16(af[i], bf[j], acc[i][j], 0, 0, 0);
  }

#pragma unroll
  for (int i = 0; i < 4; i++)
#pragma unroll
    for (int r = 0; r < 4; r++) {
      CT* Cp = C + (size_t)(row0 + wm + i * 16 + quad * 4 + r) * ldc + col0 + wn + c;
#pragma unroll
      for (int j = 0; j < 4; j++)
        Cp[j * 16] = (CT)acc[i][j][r];
    }
}

__global__ __launch_bounds__(256) void qkv_gemm_h(
    const half_t* __restrict__ xh,
    const half_t* __restrict__ Wqt, const half_t* __restrict__ Wkt,
    const half_t* __restrict__ Wvt,
    half_t* __restrict__ qh, half_t* __restrict__ kh, half_t* __restrict__ vh)
{
  int bx = blockIdx.x;
  const half_t* Bt; half_t* C; int ldc, col0;
  if (bx < 16)      { Bt = Wqt; C = qh; ldc = H_ * HD_;   col0 = bx * 128; }
  else if (bx < 20) { Bt = Wkt; C = kh; ldc = HKV_ * HD_; col0 = (bx - 16) * 128; }
  else              { Bt = Wvt; C = vh; ldc = HKV_ * HD_; col0 = (bx - 20) * 128; }
  gemm_tile_f16<half_t>(xh, Bt, C, D_, ldc, blockIdx.y * 128, col0);
}

__global__ __launch_bounds__(256) void out_gemm_h(
    const half_t* __restrict__ attn, const half_t* __restrict__ Wot,
    float* __restrict__ out)
{
  gemm_tile_f16<float>(attn, Wot, out, H_ * HD_, D_, blockIdx.y * 128, blockIdx.x * 128);
}

// ---------------------------------------------------------------------------
// In-place per-head RMS norm + RoPE on fp16 buffer. One wave per (token, head).
// ---------------------------------------------------------------------------
__global__ __launch_bounds__(256) void norm_rope_h(
    half_t* __restrict__ buf, const float* __restrict__ w,
    int nheads, int lognh, float oscale)
{
  int gid  = blockIdx.x * 256 + threadIdx.x;
  int wave = gid >> 6;
  int lane = threadIdx.x & 63;
  int head  = wave & (nheads - 1);
  int token = wave >> lognh;
  int l     = token & (L_ - 1);

  size_t idx = (size_t)token * (nheads * HD_) + head * HD_ + lane;
  float x = (float)buf[idx];

  float ss = x * x;
#pragma unroll
  for (int off = 32; off; off >>= 1) ss += __shfl_xor(ss, off);
  float xn = x * rsqrtf(ss * (1.0f / HD_) + EPS_) * w[lane];

  float partner = __shfl_xor(xn, 32);
  int   fi = lane & 31;
  float inv_freq = powf(1.0e6f, -(float)(2 * fi) * (1.0f / HD_));
  float ang = (float)l * inv_freq;
  float cv = cosf(ang), sv = sinf(ang);
  float res = (lane < 32) ? (xn * cv - partner * sv) : (xn * cv + partner * sv);
  buf[idx] = (half_t)(res * oscale);
}

// ---------------------------------------------------------------------------
// V fp16 token-major [b*L][HKV*64] -> Vt[(b*8+kvh)*64+d][2048] fp16
// with per-64-token-tile permutation k' = (k&15)*4 + (k>>4).
// ---------------------------------------------------------------------------
__global__ __launch_bounds__(256) void transpose_v_h(
    const half_t* __restrict__ vh, half_t* __restrict__ vt)
{
  int t   = threadIdx.x;
  int kk0 = blockIdx.x * 64, kvh = blockIdx.y, b = blockIdx.z;
  int d = t >> 2, uu = t & 3;
  const half_t* src = vh + (size_t)(b * L_) * (HKV_ * HD_) + kvh * HD_ + d;
  half_t* dst = vt + ((size_t)((b * HKV_ + kvh) * HD_ + d)) * L_ + kk0 + uu * 16;
  half_t vals[16];
#pragma unroll
  for (int u = 0; u < 16; u++) {
    int kp = uu * 16 + u;
    int ko = (kp & 3) * 16 + (kp >> 2);
    vals[u] = src[(size_t)(kk0 + ko) * (HKV_ * HD_)];
  }
#pragma unroll
  for (int u = 0; u < 16; u += 4)
    *(half4_t*)&dst[u] = *(half4_t*)&vals[u];
}

// ---------------------------------------------------------------------------
// MFMA flash attention (fp16). BQ = BK = 64, 4 waves, wave w owns 16 q-rows.
// ---------------------------------------------------------------------------
__global__ __launch_bounds__(256) void flash_mfma_h(
    const half_t* __restrict__ Qh, const half_t* __restrict__ Kh,
    const half_t* __restrict__ Vt, half_t* __restrict__ Oa)
{
  __shared__ half_t Ks[64][72];
  __shared__ half_t Vs[64][72];
  __shared__ half_t Ps[64][72];

  const int t    = threadIdx.x;
  const int w    = t >> 6;
  const int lane = t & 63;
  const int quad = lane >> 4;
  const int c    = lane & 15;
  const int qb = blockIdx.x, h = blockIdx.y, b = blockIdx.z;
  const int kvh = h >> 2;
  const int q0  = qb * 64;

  const half_t* qp = Qh + ((size_t)(b * L_ + q0 + w * 16 + c)) * (H_ * HD_) + h * HD_;
  half8_t qf0 = *(const half8_t*)&qp[quad * 8];
  half8_t qf1 = *(const half8_t*)&qp[32 + quad * 8];

  float4_t o[4];
#pragma unroll
  for (int i = 0; i < 4; i++) o[i] = (float4_t){0.f, 0.f, 0.f, 0.f};
  float mm[4], ll[4];
#pragma unroll
  for (int r = 0; r < 4; r++) { mm[r] = -__builtin_inff(); ll[r] = 0.f; }

  const half_t* kbase = Kh + (size_t)(b * L_) * (HKV_ * HD_) + kvh * HD_;
  const half_t* vbase = Vt + (size_t)((b * HKV_ + kvh) * HD_) * L_;

  const int sr = t >> 2, su = t & 3;

  for (int kt = 0; kt <= qb; kt++) {
    const int kk0 = kt * 64;
    __syncthreads();
    {
      const half_t* ksrc = kbase + (size_t)(kk0 + sr) * (HKV_ * HD_) + su * 16;
      *(half8_t*)&Ks[sr][su * 16]     = *(const half8_t*)&ksrc[0];
      *(half8_t*)&Ks[sr][su * 16 + 8] = *(const half8_t*)&ksrc[8];
      const half_t* vsrc = vbase + (size_t)sr * L_ + kk0 + su * 16;
      *(half8_t*)&Vs[sr][su * 16]     = *(const half8_t*)&vsrc[0];
      *(half8_t*)&Vs[sr][su * 16 + 8] = *(const half8_t*)&vsrc[8];
    }
    __syncthreads();

    float4_t S[4];
#pragma unroll
    for (int tt = 0; tt < 4; tt++) {
      half8_t kf0 = *(const half8_t*)&Ks[tt * 16 + c][quad * 8];
      half8_t kf1 = *(const half8_t*)&Ks[tt * 16 + c][32 + quad * 8];
      float4_t s = (float4_t){0.f, 0.f, 0.f, 0.f};
      s = __builtin_amdgcn_mfma_f32_16x16x32_f16(qf0, kf0, s, 0, 0, 0);
      s = __builtin_amdgcn_mfma_f32_16x16x32_f16(qf1, kf1, s, 0, 0, 0);
      S[tt] = s;
    }

    if (kt == qb) {
#pragma unroll
      for (int tt = 0; tt < 4; tt++)
#pragma unroll
        for (int r = 0; r < 4; r++) {
          int kg = kk0 + tt * 16 + c;
          int qg = q0 + w * 16 + quad * 4 + r;
          if (kg > qg) S[tt][r] = -__builtin_inff();
        }
    }

#pragma unroll
    for (int r = 0; r < 4; r++) {
      float mloc = fmaxf(fmaxf(S[0][r], S[1][r]), fmaxf(S[2][r], S[3][r]));
      mloc = fmaxf(mloc, __shfl_xor(mloc, 1));
      mloc = fmaxf(mloc, __shfl_xor(mloc, 2));
      mloc = fmaxf(mloc, __shfl_xor(mloc, 4));
      mloc = fmaxf(mloc, __shfl_xor(mloc, 8));
      float mnew = fmaxf(mm[r], mloc);
      float al = __expf(mm[r] - mnew);
      float p0 = __expf(S[0][r] - mnew);
      float p1 = __expf(S[1][r] - mnew);
      float p2 = __expf(S[2][r] - mnew);
      float p3 = __expf(S[3][r] - mnew);
      float ls = p0 + p1 + p2 + p3;
      ls += __shfl_xor(ls, 1);
      ls += __shfl_xor(ls, 2);
      ls += __shfl_xor(ls, 4);
      ls += __shfl_xor(ls, 8);
      ll[r] = ll[r] * al + ls;
      mm[r] = mnew;
#pragma unroll
      for (int tt = 0; tt < 4; tt++) o[tt][r] *= al;
      half_t pk[4] = { (half_t)p0, (half_t)p1, (half_t)p2, (half_t)p3 };
      *(half4_t*)&Ps[w * 16 + quad * 4 + r][c * 4] = *(half4_t*)&pk[0];
    }

    half8_t pf0 = *(const half8_t*)&Ps[w * 16 + c][quad * 8];
    half8_t pf1 = *(const half8_t*)&Ps[w * 16 + c][32 + quad * 8];
#pragma unroll
    for (int tt = 0; tt < 4; tt++) {
      half8_t vf0 = *(const half8_t*)&Vs[tt * 16 + c][quad * 8];
      half8_t vf1 = *(const half8_t*)&Vs[tt * 16 + c][32 + quad * 8];
      o[tt] = __builtin_amdgcn_mfma_f32_16x16x32_f16(pf0, vf0, o[tt], 0, 0, 0);
      o[tt] = __builtin_amdgcn_mfma_f32_16x16x32_f16(pf1, vf1, o[tt], 0, 0, 0);
    }
  }

  half_t* op = Oa + ((size_t)(b * L_ + q0 + w * 16 + quad * 4)) * (H_ * HD_) + h * HD_ + c;
#pragma unroll
  for (int r = 0; r < 4; r++) {
    float inv = 1.0f / ll[r];
#pragma unroll
    for (int tt = 0; tt < 4; tt++)
      op[(size_t)r * (H_ * HD_) + tt * 16] = (half_t)(o[tt][r] * inv);
  }
}

// ---------------------------------------------------------------------------
extern "C" void kernel_launch(void* const* d_in, const int* in_sizes, int n_in,
                              void* d_out, int out_size, void* d_ws, size_t ws_size,
                              hipStream_t stream)
{
  const float* x  = (const float*)d_in[0];
  const float* Wq = (const float*)d_in[1];
  const float* Wk = (const float*)d_in[2];
  const float* Wv = (const float*)d_in[3];
  const float* Wo = (const float*)d_in[4];
  const float* qw = (const float*)d_in[5];
  const float* kw = (const float*)d_in[6];
  float* out = (float*)d_out;

  const size_t XN = (size_t)B_ * L_ * D_;          // 8M
  const size_t QN = (size_t)B_ * L_ * H_ * HD_;    // 8M
  const size_t KN = (size_t)B_ * L_ * HKV_ * HD_;  // 2M
  const size_t WQ = (size_t)D_ * H_ * HD_;         // 4M
  const size_t WK = (size_t)D_ * HKV_ * HD_;       // 1M

  half_t* p   = (half_t*)d_ws;
  half_t* xh  = p;  p += XN;   // also reused as attn output
  half_t* Wqt = p;  p += WQ;
  half_t* Wkt = p;  p += WK;
  half_t* Wvt = p;  p += WK;
  half_t* Wot = p;  p += WQ;
  half_t* qh  = p;  p += QN;
  half_t* kh  = p;  p += KN;
  half_t* vh  = p;  p += KN;
  half_t* vt  = p;  p += KN;
  half_t* attn = xh;           // xh dead after qkv_gemm_h

  // 0) conversions / weight transposes
  convert_f32_f16<<<XN / 2048, 256, 0, stream>>>(x, xh);
  transpose_convert<<<dim3(64, 64), 256, 0, stream>>>(Wq, Wqt, H_ * HD_,   D_);
  transpose_convert<<<dim3(64, 16), 256, 0, stream>>>(Wk, Wkt, HKV_ * HD_, D_);
  transpose_convert<<<dim3(64, 16), 256, 0, stream>>>(Wv, Wvt, HKV_ * HD_, D_);
  transpose_convert<<<dim3(64, 64), 256, 0, stream>>>(Wo, Wot, D_, H_ * HD_);

  // 1) QKV projections (fp16 MFMA)
  qkv_gemm_h<<<dim3(24, 32), 256, 0, stream>>>(xh, Wqt, Wkt, Wvt, qh, kh, vh);

  // 2) RMS norm + RoPE in place (Q gets softmax scale folded)
  norm_rope_h<<<(B_ * L_ * H_) / 4, 256, 0, stream>>>(qh, qw, H_, 5, 0.125f);
  norm_rope_h<<<(B_ * L_ * HKV_) / 4, 256, 0, stream>>>(kh, kw, HKV_, 3, 1.0f);

  // 3) V -> transposed+permuted
  transpose_v_h<<<dim3(L_ / 64, HKV_, B_), 256, 0, stream>>>(vh, vt);

  // 4) MFMA flash attention
  flash_mfma_h<<<dim3(L_ / 64, H_, B_), 256, 0, stream>>>(qh, kh, vt, attn);

  // 5) output projection (fp16 MFMA, fp32 out)
  out_gemm_h<<<dim3(16, 32), 256, 0, stream>>>(attn, Wot, out);
}

// Round 4
// 447.075 us; speedup vs baseline: 6.4022x; 1.1311x over previous
//
#include <hip/hip_runtime.h>
#include <math.h>

#define B_ 2
#define L_ 2048
#define D_ 2048
#define H_ 32
#define HKV_ 8
#define HD_ 64
#define EPS_ 1e-5f

typedef _Float16 half_t;
typedef __attribute__((ext_vector_type(8))) _Float16 half8_t;
typedef __attribute__((ext_vector_type(4))) _Float16 half4_t;
typedef __attribute__((ext_vector_type(4))) float float4_t;

__device__ __forceinline__ float4_t fmax4(float4_t a, float4_t b) {
  float4_t r;
  r[0] = fmaxf(a[0], b[0]); r[1] = fmaxf(a[1], b[1]);
  r[2] = fmaxf(a[2], b[2]); r[3] = fmaxf(a[3], b[3]);
  return r;
}

// ---------------------------------------------------------------------------
// fp32 -> fp16 straight convert (8 elems/thread)
// ---------------------------------------------------------------------------
__global__ __launch_bounds__(256) void convert_f32_f16(
    const float* __restrict__ in, half_t* __restrict__ out)
{
  size_t i = ((size_t)blockIdx.x * 256 + threadIdx.x) * 8;
  float4 v0 = *(const float4*)&in[i];
  float4 v1 = *(const float4*)&in[i + 4];
  half8_t h;
  h[0] = (half_t)v0.x; h[1] = (half_t)v0.y; h[2] = (half_t)v0.z; h[3] = (half_t)v0.w;
  h[4] = (half_t)v1.x; h[5] = (half_t)v1.y; h[6] = (half_t)v1.z; h[7] = (half_t)v1.w;
  *(half8_t*)&out[i] = h;
}

// ---------------------------------------------------------------------------
// W[K][N] fp32 -> Wt[N][K] fp16 (32x32 LDS tile transpose)
// ---------------------------------------------------------------------------
__global__ __launch_bounds__(256) void transpose_convert(
    const float* __restrict__ W, half_t* __restrict__ Wt, int N, int K)
{
  __shared__ float tile[32][33];
  int k0 = blockIdx.x * 32, n0 = blockIdx.y * 32;
  int tx = threadIdx.x & 31, ty = threadIdx.x >> 5;
#pragma unroll
  for (int i = 0; i < 4; i++)
    tile[ty + i * 8][tx] = W[(size_t)(k0 + ty + i * 8) * N + n0 + tx];
  __syncthreads();
#pragma unroll
  for (int i = 0; i < 4; i++)
    Wt[(size_t)(n0 + ty + i * 8) * K + k0 + tx] = (half_t)tile[tx][ty + i * 8];
}

// ---------------------------------------------------------------------------
// fp16 MFMA GEMM (unchanged): C[row0:+128][col0:+128] = A[M][K] @ Bt[N][K]^T
// ---------------------------------------------------------------------------
template <typename CT>
__device__ __forceinline__ void gemm_tile_f16(
    const half_t* __restrict__ A, const half_t* __restrict__ Bt,
    CT* __restrict__ C, int K, int ldc, int row0, int col0)
{
  __shared__ half_t As[128][40];
  __shared__ half_t Bs[128][40];
  const int t    = threadIdx.x;
  const int lane = t & 63;
  const int w    = t >> 6;
  const int quad = lane >> 4, c = lane & 15;
  const int wm = (w >> 1) * 64, wn = (w & 1) * 64;

  float4_t acc[4][4];
#pragma unroll
  for (int i = 0; i < 4; i++)
#pragma unroll
    for (int j = 0; j < 4; j++) acc[i][j] = (float4_t){0.f, 0.f, 0.f, 0.f};

  const int sr = t >> 1;
  const int sc = (t & 1) * 16;
  const half_t* Ap = A  + (size_t)(row0 + sr) * K + sc;
  const half_t* Bp = Bt + (size_t)(col0 + sr) * K + sc;

  for (int k0 = 0; k0 < K; k0 += 32) {
    half8_t a0 = *(const half8_t*)&Ap[k0];
    half8_t a1 = *(const half8_t*)&Ap[k0 + 8];
    half8_t b0 = *(const half8_t*)&Bp[k0];
    half8_t b1 = *(const half8_t*)&Bp[k0 + 8];
    __syncthreads();
    *(half8_t*)&As[sr][sc]     = a0;
    *(half8_t*)&As[sr][sc + 8] = a1;
    *(half8_t*)&Bs[sr][sc]     = b0;
    *(half8_t*)&Bs[sr][sc + 8] = b1;
    __syncthreads();

    half8_t af[4], bf[4];
#pragma unroll
    for (int i = 0; i < 4; i++) af[i] = *(const half8_t*)&As[wm + i * 16 + c][quad * 8];
#pragma unroll
    for (int j = 0; j < 4; j++) bf[j] = *(const half8_t*)&Bs[wn + j * 16 + c][quad * 8];
#pragma unroll
    for (int i = 0; i < 4; i++)
#pragma unroll
      for (int j = 0; j < 4; j++)
        acc[i][j] = __builtin_amdgcn_mfma_f32_16x16x32_f16(af[i], bf[j], acc[i][j], 0, 0, 0);
  }

#pragma unroll
  for (int i = 0; i < 4; i++)
#pragma unroll
    for (int r = 0; r < 4; r++) {
      CT* Cp = C + (size_t)(row0 + wm + i * 16 + quad * 4 + r) * ldc + col0 + wn + c;
#pragma unroll
      for (int j = 0; j < 4; j++)
        Cp[j * 16] = (CT)acc[i][j][r];
    }
}

__global__ __launch_bounds__(256) void qkv_gemm_h(
    const half_t* __restrict__ xh,
    const half_t* __restrict__ Wqt, const half_t* __restrict__ Wkt,
    const half_t* __restrict__ Wvt,
    half_t* __restrict__ qh, half_t* __restrict__ kh, half_t* __restrict__ vh)
{
  int bx = blockIdx.x;
  const half_t* Bt; half_t* C; int ldc, col0;
  if (bx < 16)      { Bt = Wqt; C = qh; ldc = H_ * HD_;   col0 = bx * 128; }
  else if (bx < 20) { Bt = Wkt; C = kh; ldc = HKV_ * HD_; col0 = (bx - 16) * 128; }
  else              { Bt = Wvt; C = vh; ldc = HKV_ * HD_; col0 = (bx - 20) * 128; }
  gemm_tile_f16<half_t>(xh, Bt, C, D_, ldc, blockIdx.y * 128, col0);
}

__global__ __launch_bounds__(256) void out_gemm_h(
    const half_t* __restrict__ attn, const half_t* __restrict__ Wot,
    float* __restrict__ out)
{
  gemm_tile_f16<float>(attn, Wot, out, H_ * HD_, D_, blockIdx.y * 128, blockIdx.x * 128);
}

// ---------------------------------------------------------------------------
// In-place per-head RMS norm + RoPE on fp16 buffer. One wave per (token, head).
// Q gets softmax scale * log2(e) folded (exp2-domain softmax downstream).
// ---------------------------------------------------------------------------
__global__ __launch_bounds__(256) void norm_rope_h(
    half_t* __restrict__ buf, const float* __restrict__ w,
    int nheads, int lognh, float oscale)
{
  int gid  = blockIdx.x * 256 + threadIdx.x;
  int wave = gid >> 6;
  int lane = threadIdx.x & 63;
  int head  = wave & (nheads - 1);
  int token = wave >> lognh;
  int l     = token & (L_ - 1);

  size_t idx = (size_t)token * (nheads * HD_) + head * HD_ + lane;
  float x = (float)buf[idx];

  float ss = x * x;
#pragma unroll
  for (int off = 32; off; off >>= 1) ss += __shfl_xor(ss, off);
  float xn = x * rsqrtf(ss * (1.0f / HD_) + EPS_) * w[lane];

  float partner = __shfl_xor(xn, 32);
  int   fi = lane & 31;
  // theta^(-2fi/64) = 2^(fi * -log2(1e6)/32)
  float inv_freq = exp2f((float)fi * -0.622862853f);
  float ang = (float)l * inv_freq;
  float cv = cosf(ang), sv = sinf(ang);
  float res = (lane < 32) ? (xn * cv - partner * sv) : (xn * cv + partner * sv);
  buf[idx] = (half_t)(res * oscale);
}

// ---------------------------------------------------------------------------
// V fp16 token-major [b*L][HKV*64] -> Vt[(b*8+kvh)*64+d][2048] (plain transpose)
// ---------------------------------------------------------------------------
__global__ __launch_bounds__(256) void transpose_v_h(
    const half_t* __restrict__ vh, half_t* __restrict__ vt)
{
  int t   = threadIdx.x;
  int kk0 = blockIdx.x * 64, kvh = blockIdx.y, b = blockIdx.z;
  int d = t >> 2, uu = t & 3;
  const half_t* src = vh + (size_t)(b * L_) * (HKV_ * HD_) + kvh * HD_ + d;
  half_t* dst = vt + ((size_t)((b * HKV_ + kvh) * HD_ + d)) * L_ + kk0 + uu * 16;
  half_t vals[16];
#pragma unroll
  for (int u = 0; u < 16; u++)
    vals[u] = src[(size_t)(kk0 + uu * 16 + u) * (HKV_ * HD_)];
#pragma unroll
  for (int u = 0; u < 16; u += 4)
    *(half4_t*)&dst[u] = *(half4_t*)&vals[u];
}

// ---------------------------------------------------------------------------
// MFMA flash attention v2. BQ=128 (4 waves x 32 q-rows), BK=64.
// S^T = K Q^T so the k-reduction is within-lane; P^T written to LDS in
// natural k-order; per-row alpha/l broadcast through LDS (same-wave only).
// exp2-domain softmax (log2e folded into Q scale upstream).
// ---------------------------------------------------------------------------
__global__ __launch_bounds__(256) void flash_mfma2(
    const half_t* __restrict__ Qh, const half_t* __restrict__ Kh,
    const half_t* __restrict__ Vt, half_t* __restrict__ Oa)
{
  __shared__ __align__(16) half_t Ks[64][72];   // [k-token][d]
  __shared__ __align__(16) half_t Vs[64][72];   // [d][k-token]
  __shared__ __align__(16) half_t Ps[128][72];  // [q-local][k-local], per-wave rows
  __shared__ __align__(16) float  Ab[128];      // per-row alpha / l broadcast

  const int t    = threadIdx.x;
  const int w    = t >> 6;
  const int lane = t & 63;
  const int quad = lane >> 4;
  const int c    = lane & 15;
  const int qb = (int)gridDim.x - 1 - (int)blockIdx.x;  // heavy blocks first
  const int h = blockIdx.y, b = blockIdx.z;
  const int kvh = h >> 2;
  const int q0  = qb * 128;
  const int wq0 = q0 + w * 32;      // this wave's first q row

  // Q fragments in registers for whole block: B-operand [n=q][k=d]
  half8_t qf[2][2];
#pragma unroll
  for (int u = 0; u < 2; u++) {
    const half_t* qp = Qh + ((size_t)(b * L_ + wq0 + u * 16 + c)) * (H_ * HD_) + h * HD_;
    qf[u][0] = *(const half8_t*)&qp[quad * 8];
    qf[u][1] = *(const half8_t*)&qp[32 + quad * 8];
  }

  float4_t o[2][4];
#pragma unroll
  for (int u = 0; u < 2; u++)
#pragma unroll
    for (int dt = 0; dt < 4; dt++) o[u][dt] = (float4_t){0.f, 0.f, 0.f, 0.f};
  float mm[2] = {-__builtin_inff(), -__builtin_inff()};
  float ll[2] = {0.f, 0.f};

  const half_t* kbase = Kh + (size_t)(b * L_) * (HKV_ * HD_) + kvh * HD_;
  const half_t* vbase = Vt + (size_t)((b * HKV_ + kvh) * HD_) * L_;
  const int sr = t >> 2, su = (t & 3) * 16;

  // prefetch tile 0
  half8_t kr0, kr1, vr0, vr1;
  {
    const half_t* kp = kbase + (size_t)sr * (HKV_ * HD_) + su;
    kr0 = *(const half8_t*)kp;  kr1 = *(const half8_t*)(kp + 8);
    const half_t* vp = vbase + (size_t)sr * L_ + su;
    vr0 = *(const half8_t*)vp;  vr1 = *(const half8_t*)(vp + 8);
  }

  const int last = (q0 + 127) >> 6;
  for (int kt = 0; kt <= last; kt++) {
    const int kk0 = kt * 64;
    __syncthreads();
    *(half8_t*)&Ks[sr][su]     = kr0;
    *(half8_t*)&Ks[sr][su + 8] = kr1;
    *(half8_t*)&Vs[sr][su]     = vr0;
    *(half8_t*)&Vs[sr][su + 8] = vr1;
    __syncthreads();
    if (kt < last) {   // prefetch next tile while computing this one
      const half_t* kp = kbase + (size_t)(kk0 + 64 + sr) * (HKV_ * HD_) + su;
      kr0 = *(const half8_t*)kp;  kr1 = *(const half8_t*)(kp + 8);
      const half_t* vp = vbase + (size_t)sr * L_ + kk0 + 64 + su;
      vr0 = *(const half8_t*)vp;  vr1 = *(const half8_t*)(vp + 8);
    }
    if (kk0 > wq0 + 31) continue;   // tile fully above diagonal for this wave

    // S^T[k][q] = K Q^T : A = K frag, B = Q frag
    float4_t S[2][4];
#pragma unroll
    for (int tt = 0; tt < 4; tt++) {
      half8_t kf0 = *(const half8_t*)&Ks[tt * 16 + c][quad * 8];
      half8_t kf1 = *(const half8_t*)&Ks[tt * 16 + c][32 + quad * 8];
#pragma unroll
      for (int u = 0; u < 2; u++) {
        float4_t s = (float4_t){0.f, 0.f, 0.f, 0.f};
        s = __builtin_amdgcn_mfma_f32_16x16x32_f16(kf0, qf[u][0], s, 0, 0, 0);
        s = __builtin_amdgcn_mfma_f32_16x16x32_f16(kf1, qf[u][1], s, 0, 0, 0);
        S[u][tt] = s;
      }
    }

    // causal mask (only near-diagonal tiles): element k = kk0+tt*16+quad*4+r,
    // q = wq0+u*16+c
    if (kk0 + 63 > wq0) {
#pragma unroll
      for (int u = 0; u < 2; u++)
#pragma unroll
        for (int tt = 0; tt < 4; tt++) {
          int base = kk0 + tt * 16 + quad * 4 - (wq0 + u * 16 + c);
#pragma unroll
          for (int r = 0; r < 4; r++)
            if (base + r > 0) S[u][tt][r] = -__builtin_inff();
        }
    }

    // online softmax (within-lane over 16 k, then 2 shuffles across quads)
#pragma unroll
    for (int u = 0; u < 2; u++) {
      float4_t m4 = fmax4(fmax4(S[u][0], S[u][1]), fmax4(S[u][2], S[u][3]));
      float mloc = fmaxf(fmaxf(m4[0], m4[1]), fmaxf(m4[2], m4[3]));
      mloc = fmaxf(mloc, __shfl_xor(mloc, 16));
      mloc = fmaxf(mloc, __shfl_xor(mloc, 32));
      float mnew = fmaxf(mm[u], mloc);
      float al = exp2f(mm[u] - mnew);
      mm[u] = mnew;
#pragma unroll
      for (int tt = 0; tt < 4; tt++) {
#pragma unroll
        for (int r = 0; r < 4; r++) S[u][tt][r] = exp2f(S[u][tt][r] - mnew);
        half4_t pv;
#pragma unroll
        for (int r = 0; r < 4; r++) pv[r] = (half_t)S[u][tt][r];
        *(half4_t*)&Ps[w * 32 + u * 16 + c][tt * 16 + quad * 4] = pv;
      }
      float4_t s4 = S[u][0] + S[u][1] + S[u][2] + S[u][3];
      float ls = (s4[0] + s4[1]) + (s4[2] + s4[3]);
      ls += __shfl_xor(ls, 16);
      ls += __shfl_xor(ls, 32);
      ll[u] = ll[u] * al + ls;
      if (quad == 0) Ab[w * 32 + u * 16 + c] = al;   // broadcast alpha per q-row
    }

    // rescale O by alpha of its own rows (q = wq0 + u*16 + quad*4 + r)
#pragma unroll
    for (int u = 0; u < 2; u++) {
      float4_t av = *(const float4_t*)&Ab[w * 32 + u * 16 + quad * 4];
#pragma unroll
      for (int dt = 0; dt < 4; dt++)
#pragma unroll
        for (int r = 0; r < 4; r++) o[u][dt][r] *= av[r];
    }

    // O += P V : A = P frag [q][k], B = V frag [k][d] from Vs[d][k]
    half8_t pf[2][2];
#pragma unroll
    for (int u = 0; u < 2; u++) {
      pf[u][0] = *(const half8_t*)&Ps[w * 32 + u * 16 + c][quad * 8];
      pf[u][1] = *(const half8_t*)&Ps[w * 32 + u * 16 + c][32 + quad * 8];
    }
#pragma unroll
    for (int dt = 0; dt < 4; dt++) {
      half8_t vf0 = *(const half8_t*)&Vs[dt * 16 + c][quad * 8];
      half8_t vf1 = *(const half8_t*)&Vs[dt * 16 + c][32 + quad * 8];
#pragma unroll
      for (int u = 0; u < 2; u++) {
        o[u][dt] = __builtin_amdgcn_mfma_f32_16x16x32_f16(pf[u][0], vf0, o[u][dt], 0, 0, 0);
        o[u][dt] = __builtin_amdgcn_mfma_f32_16x16x32_f16(pf[u][1], vf1, o[u][dt], 0, 0, 0);
      }
    }
  }

  // epilogue: broadcast l per q-row, normalize, store
#pragma unroll
  for (int u = 0; u < 2; u++)
    if (quad == 0) Ab[w * 32 + u * 16 + c] = ll[u];
#pragma unroll
  for (int u = 0; u < 2; u++) {
    float4_t lv = *(const float4_t*)&Ab[w * 32 + u * 16 + quad * 4];
#pragma unroll
    for (int r = 0; r < 4; r++) {
      float inv = 1.0f / lv[r];
      half_t* op = Oa + ((size_t)(b * L_ + wq0 + u * 16 + quad * 4 + r)) * (H_ * HD_)
                 + h * HD_ + c;
#pragma unroll
      for (int dt = 0; dt < 4; dt++)
        op[dt * 16] = (half_t)(o[u][dt][r] * inv);
    }
  }
}

// ---------------------------------------------------------------------------
extern "C" void kernel_launch(void* const* d_in, const int* in_sizes, int n_in,
                              void* d_out, int out_size, void* d_ws, size_t ws_size,
                              hipStream_t stream)
{
  const float* x  = (const float*)d_in[0];
  const float* Wq = (const float*)d_in[1];
  const float* Wk = (const float*)d_in[2];
  const float* Wv = (const float*)d_in[3];
  const float* Wo = (const float*)d_in[4];
  const float* qw = (const float*)d_in[5];
  const float* kw = (const float*)d_in[6];
  float* out = (float*)d_out;

  const size_t XN = (size_t)B_ * L_ * D_;          // 8M
  const size_t QN = (size_t)B_ * L_ * H_ * HD_;    // 8M
  const size_t KN = (size_t)B_ * L_ * HKV_ * HD_;  // 2M
  const size_t WQ = (size_t)D_ * H_ * HD_;         // 4M
  const size_t WK = (size_t)D_ * HKV_ * HD_;       // 1M

  half_t* p   = (half_t*)d_ws;
  half_t* xh  = p;  p += XN;   // reused as attn output
  half_t* Wqt = p;  p += WQ;
  half_t* Wkt = p;  p += WK;
  half_t* Wvt = p;  p += WK;
  half_t* Wot = p;  p += WQ;
  half_t* qh  = p;  p += QN;
  half_t* kh  = p;  p += KN;
  half_t* vh  = p;  p += KN;
  half_t* vt  = p;  p += KN;
  half_t* attn = xh;           // xh dead after qkv_gemm_h

  // 0) conversions / weight transposes
  convert_f32_f16<<<XN / 2048, 256, 0, stream>>>(x, xh);
  transpose_convert<<<dim3(64, 64), 256, 0, stream>>>(Wq, Wqt, H_ * HD_,   D_);
  transpose_convert<<<dim3(64, 16), 256, 0, stream>>>(Wk, Wkt, HKV_ * HD_, D_);
  transpose_convert<<<dim3(64, 16), 256, 0, stream>>>(Wv, Wvt, HKV_ * HD_, D_);
  transpose_convert<<<dim3(64, 64), 256, 0, stream>>>(Wo, Wot, D_, H_ * HD_);

  // 1) QKV projections (fp16 MFMA)
  qkv_gemm_h<<<dim3(24, 32), 256, 0, stream>>>(xh, Wqt, Wkt, Wvt, qh, kh, vh);

  // 2) RMS norm + RoPE in place; Q scale = 0.125 * log2(e) for exp2 softmax
  norm_rope_h<<<(B_ * L_ * H_) / 4, 256, 0, stream>>>(qh, qw, H_, 5, 0.180336880f);
  norm_rope_h<<<(B_ * L_ * HKV_) / 4, 256, 0, stream>>>(kh, kw, HKV_, 3, 1.0f);

  // 3) V -> transposed
  transpose_v_h<<<dim3(L_ / 64, HKV_, B_), 256, 0, stream>>>(vh, vt);

  // 4) MFMA flash attention v2 (BQ=128)
  flash_mfma2<<<dim3(L_ / 128, H_, B_), 256, 0, stream>>>(qh, kh, vt, attn);

  // 5) output projection (fp16 MFMA, fp32 out)
  out_gemm_h<<<dim3(16, 32), 256, 0, stream>>>(attn, Wot, out);
}

// Round 7
// 410.250 us; speedup vs baseline: 6.9769x; 1.0898x over previous
//
#include <hip/hip_runtime.h>
#include <math.h>

#define B_ 2
#define L_ 2048
#define D_ 2048
#define H_ 32
#define HKV_ 8
#define HD_ 64
#define EPS_ 1e-5f

typedef _Float16 half_t;
typedef __attribute__((ext_vector_type(8))) _Float16 half8_t;
typedef __attribute__((ext_vector_type(4))) _Float16 half4_t;
typedef __attribute__((ext_vector_type(4))) float float4_t;

__device__ __forceinline__ float4_t fmax4(float4_t a, float4_t b) {
  float4_t r;
  r[0] = fmaxf(a[0], b[0]); r[1] = fmaxf(a[1], b[1]);
  r[2] = fmaxf(a[2], b[2]); r[3] = fmaxf(a[3], b[3]);
  return r;
}

// ---------------------------------------------------------------------------
// prep_all: fused x->fp16 convert + 4 weight transpose/converts (one launch).
// ---------------------------------------------------------------------------
__global__ __launch_bounds__(256) void prep_all(
    const float* __restrict__ x,
    const float* __restrict__ Wq, const float* __restrict__ Wk,
    const float* __restrict__ Wv, const float* __restrict__ Wo,
    half_t* __restrict__ xh,
    half_t* __restrict__ Wqt, half_t* __restrict__ Wkt,
    half_t* __restrict__ Wvt, half_t* __restrict__ Wot)
{
  __shared__ float tile[64][65];
  const int t = threadIdx.x;
  int id = blockIdx.x;

  if (id < 4096) {           // x convert: 8 elems/thread
    size_t i = ((size_t)id * 256 + t) * 8;
    float4 v0 = *(const float4*)&x[i];
    float4 v1 = *(const float4*)&x[i + 4];
    half8_t h;
    h[0] = (half_t)v0.x; h[1] = (half_t)v0.y; h[2] = (half_t)v0.z; h[3] = (half_t)v0.w;
    h[4] = (half_t)v1.x; h[5] = (half_t)v1.y; h[6] = (half_t)v1.z; h[7] = (half_t)v1.w;
    *(half8_t*)&xh[i] = h;
    return;
  }
  id -= 4096;
  const float* W; half_t* Wt; int N;
  if (id < 1024)      { W = Wq; Wt = Wqt; N = 2048; }
  else if (id < 1280) { id -= 1024; W = Wk; Wt = Wkt; N = 512; }
  else if (id < 1536) { id -= 1280; W = Wv; Wt = Wvt; N = 512; }
  else                { id -= 1536; W = Wo; Wt = Wot; N = 2048; }
  const int K = 2048;
  int tk = id & 31, tn = id >> 5;
  int k0 = tk * 64, n0 = tn * 64;

  int rr = t >> 6, cc = t & 63;
#pragma unroll
  for (int i = 0; i < 16; i++)
    tile[rr + i * 4][cc] = W[(size_t)(k0 + rr + i * 4) * N + n0 + cc];
  __syncthreads();

  int rn = t >> 2, q4 = (t & 3) * 16;
  half8_t h0, h1;
#pragma unroll
  for (int u = 0; u < 8; u++) h0[u] = (half_t)tile[q4 + u][rn];
#pragma unroll
  for (int u = 0; u < 8; u++) h1[u] = (half_t)tile[q4 + 8 + u][rn];
  *(half8_t*)&Wt[(size_t)(n0 + rn) * K + k0 + q4]     = h0;
  *(half8_t*)&Wt[(size_t)(n0 + rn) * K + k0 + q4 + 8] = h1;
}

// ---------------------------------------------------------------------------
// fp16 MFMA GEMM: C[row0:+128][col0:+128] = A[M][K] @ Bt[N][K]^T
// ---------------------------------------------------------------------------
template <typename CT>
__device__ __forceinline__ void gemm_tile_f16(
    const half_t* __restrict__ A, const half_t* __restrict__ Bt,
    CT* __restrict__ C, int K, int ldc, int row0, int col0)
{
  __shared__ half_t As[128][40];
  __shared__ half_t Bs[128][40];
  const int t    = threadIdx.x;
  const int lane = t & 63;
  const int w    = t >> 6;
  const int quad = lane >> 4, c = lane & 15;
  const int wm = (w >> 1) * 64, wn = (w & 1) * 64;

  float4_t acc[4][4];
#pragma unroll
  for (int i = 0; i < 4; i++)
#pragma unroll
    for (int j = 0; j < 4; j++) acc[i][j] = (float4_t){0.f, 0.f, 0.f, 0.f};

  const int sr = t >> 1;
  const int sc = (t & 1) * 16;
  const half_t* Ap = A  + (size_t)(row0 + sr) * K + sc;
  const half_t* Bp = Bt + (size_t)(col0 + sr) * K + sc;

  for (int k0 = 0; k0 < K; k0 += 32) {
    half8_t a0 = *(const half8_t*)&Ap[k0];
    half8_t a1 = *(const half8_t*)&Ap[k0 + 8];
    half8_t b0 = *(const half8_t*)&Bp[k0];
    half8_t b1 = *(const half8_t*)&Bp[k0 + 8];
    __syncthreads();
    *(half8_t*)&As[sr][sc]     = a0;
    *(half8_t*)&As[sr][sc + 8] = a1;
    *(half8_t*)&Bs[sr][sc]     = b0;
    *(half8_t*)&Bs[sr][sc + 8] = b1;
    __syncthreads();

    half8_t af[4], bf[4];
#pragma unroll
    for (int i = 0; i < 4; i++) af[i] = *(const half8_t*)&As[wm + i * 16 + c][quad * 8];
#pragma unroll
    for (int j = 0; j < 4; j++) bf[j] = *(const half8_t*)&Bs[wn + j * 16 + c][quad * 8];
#pragma unroll
    for (int i = 0; i < 4; i++)
#pragma unroll
      for (int j = 0; j < 4; j++)
        acc[i][j] = __builtin_amdgcn_mfma_f32_16x16x32_f16(af[i], bf[j], acc[i][j], 0, 0, 0);
  }

#pragma unroll
  for (int i = 0; i < 4; i++)
#pragma unroll
    for (int r = 0; r < 4; r++) {
      CT* Cp = C + (size_t)(row0 + wm + i * 16 + quad * 4 + r) * ldc + col0 + wn + c;
#pragma unroll
      for (int j = 0; j < 4; j++)
        Cp[j * 16] = (CT)acc[i][j][r];
    }
}

__global__ __launch_bounds__(256) void qkv_gemm_h(
    const half_t* __restrict__ xh,
    const half_t* __restrict__ Wqt, const half_t* __restrict__ Wkt,
    const half_t* __restrict__ Wvt,
    half_t* __restrict__ qh, half_t* __restrict__ kh, half_t* __restrict__ vh)
{
  int bx = blockIdx.x;
  const half_t* Bt; half_t* C; int ldc, col0;
  if (bx < 16)      { Bt = Wqt; C = qh; ldc = H_ * HD_;   col0 = bx * 128; }
  else if (bx < 20) { Bt = Wkt; C = kh; ldc = HKV_ * HD_; col0 = (bx - 16) * 128; }
  else              { Bt = Wvt; C = vh; ldc = HKV_ * HD_; col0 = (bx - 20) * 128; }
  gemm_tile_f16<half_t>(xh, Bt, C, D_, ldc, blockIdx.y * 128, col0);
}

__global__ __launch_bounds__(256) void out_gemm_h(
    const half_t* __restrict__ attn, const half_t* __restrict__ Wot,
    float* __restrict__ out)
{
  gemm_tile_f16<float>(attn, Wot, out, H_ * HD_, D_, blockIdx.y * 128, blockIdx.x * 128);
}

// ---------------------------------------------------------------------------
// postproc: fused RMS-norm+RoPE (q), RMS-norm+RoPE (k), V transpose
// ---------------------------------------------------------------------------
__device__ __forceinline__ void norm_rope_body(
    half_t* buf, const float* w, int wave, int nheads, int lognh,
    int lane, float oscale)
{
  int head  = wave & (nheads - 1);
  int token = wave >> lognh;
  int l     = token & (L_ - 1);

  size_t idx = (size_t)token * (nheads * HD_) + head * HD_ + lane;
  float x = (float)buf[idx];

  float ss = x * x;
#pragma unroll
  for (int off = 32; off; off >>= 1) ss += __shfl_xor(ss, off);
  float xn = x * rsqrtf(ss * (1.0f / HD_) + EPS_) * w[lane];

  float partner = __shfl_xor(xn, 32);
  int   fi = lane & 31;
  float inv_freq = exp2f((float)fi * -0.622862853f);   // 1e6^(-2fi/64)
  float ang = (float)l * inv_freq;
  float cv = cosf(ang), sv = sinf(ang);
  float res = (lane < 32) ? (xn * cv - partner * sv) : (xn * cv + partner * sv);
  buf[idx] = (half_t)(res * oscale);
}

__global__ __launch_bounds__(256) void postproc(
    half_t* __restrict__ qh, half_t* __restrict__ kh,
    const half_t* __restrict__ vh, half_t* __restrict__ vt,
    const float* __restrict__ qw, const float* __restrict__ kw)
{
  const int t = threadIdx.x;
  int id = blockIdx.x;
  if (id < 32768) {          // q norm
    int wave = id * 4 + (t >> 6);
    norm_rope_body(qh, qw, wave, H_, 5, t & 63, 0.180336880f);  // 0.125*log2e
    return;
  }
  id -= 32768;
  if (id < 8192) {           // k norm
    int wave = id * 4 + (t >> 6);
    norm_rope_body(kh, kw, wave, HKV_, 3, t & 63, 1.0f);
    return;
  }
  id -= 8192;                // v transpose
  int kk0 = (id & 31) * 64, kvh = (id >> 5) & 7, b = id >> 8;
  int d = t >> 2, uu = t & 3;
  const half_t* src = vh + (size_t)(b * L_) * (HKV_ * HD_) + kvh * HD_ + d;
  half_t* dst = vt + ((size_t)((b * HKV_ + kvh) * HD_ + d)) * L_ + kk0 + uu * 16;
  half_t vals[16];
#pragma unroll
  for (int u = 0; u < 16; u++)
    vals[u] = src[(size_t)(kk0 + uu * 16 + u) * (HKV_ * HD_)];
#pragma unroll
  for (int u = 0; u < 16; u += 4)
    *(half4_t*)&dst[u] = *(half4_t*)&vals[u];
}

// ---------------------------------------------------------------------------
// MFMA flash attention (exact round-4 body). BQ=128 (4 waves x 32 q-rows),
// BK=64. qb swizzled by (x+y)&15 to decorrelate work from CU assignment:
// resident blocks on one CU span mixed qb -> balanced per-CU totals.
// ---------------------------------------------------------------------------
__global__ __launch_bounds__(256) void flash_mfma2(
    const half_t* __restrict__ Qh, const half_t* __restrict__ Kh,
    const half_t* __restrict__ Vt, half_t* __restrict__ Oa)
{
  __shared__ __align__(16) half_t Ks[64][72];   // [k-token][d]
  __shared__ __align__(16) half_t Vs[64][72];   // [d][k-token]
  __shared__ __align__(16) half_t Ps[128][72];  // [q-local][k-local]
  __shared__ __align__(16) float  Ab[128];      // per-row alpha / l broadcast

  const int t    = threadIdx.x;
  const int w    = t >> 6;
  const int lane = t & 63;
  const int quad = lane >> 4;
  const int c    = lane & 15;
  const int qb = ((int)blockIdx.x + (int)blockIdx.y) & 15;  // swizzle: bijective per head
  const int h = blockIdx.y, b = blockIdx.z;
  const int kvh = h >> 2;
  const int q0  = qb * 128;
  const int wq0 = q0 + w * 32;      // this wave's first q row

  // Q fragments in registers for whole block: B-operand [n=q][k=d]
  half8_t qf[2][2];
#pragma unroll
  for (int u = 0; u < 2; u++) {
    const half_t* qp = Qh + ((size_t)(b * L_ + wq0 + u * 16 + c)) * (H_ * HD_) + h * HD_;
    qf[u][0] = *(const half8_t*)&qp[quad * 8];
    qf[u][1] = *(const half8_t*)&qp[32 + quad * 8];
  }

  float4_t o[2][4];
#pragma unroll
  for (int u = 0; u < 2; u++)
#pragma unroll
    for (int dt = 0; dt < 4; dt++) o[u][dt] = (float4_t){0.f, 0.f, 0.f, 0.f};
  float mm[2] = {-__builtin_inff(), -__builtin_inff()};
  float ll[2] = {0.f, 0.f};

  const half_t* kbase = Kh + (size_t)(b * L_) * (HKV_ * HD_) + kvh * HD_;
  const half_t* vbase = Vt + (size_t)((b * HKV_ + kvh) * HD_) * L_;
  const int sr = t >> 2, su = (t & 3) * 16;

  // prefetch tile 0
  half8_t kr0, kr1, vr0, vr1;
  {
    const half_t* kp = kbase + (size_t)sr * (HKV_ * HD_) + su;
    kr0 = *(const half8_t*)kp;  kr1 = *(const half8_t*)(kp + 8);
    const half_t* vp = vbase + (size_t)sr * L_ + su;
    vr0 = *(const half8_t*)vp;  vr1 = *(const half8_t*)(vp + 8);
  }

  const int last = (q0 + 127) >> 6;
  for (int kt = 0; kt <= last; kt++) {
    const int kk0 = kt * 64;
    __syncthreads();
    *(half8_t*)&Ks[sr][su]     = kr0;
    *(half8_t*)&Ks[sr][su + 8] = kr1;
    *(half8_t*)&Vs[sr][su]     = vr0;
    *(half8_t*)&Vs[sr][su + 8] = vr1;
    __syncthreads();
    if (kt < last) {   // prefetch next tile while computing this one
      const half_t* kp = kbase + (size_t)(kk0 + 64 + sr) * (HKV_ * HD_) + su;
      kr0 = *(const half8_t*)kp;  kr1 = *(const half8_t*)(kp + 8);
      const half_t* vp = vbase + (size_t)sr * L_ + kk0 + 64 + su;
      vr0 = *(const half8_t*)vp;  vr1 = *(const half8_t*)(vp + 8);
    }
    if (kk0 > wq0 + 31) continue;   // tile fully above diagonal for this wave

    // S^T[k][q] = K Q^T : A = K frag, B = Q frag
    float4_t S[2][4];
#pragma unroll
    for (int tt = 0; tt < 4; tt++) {
      half8_t kf0 = *(const half8_t*)&Ks[tt * 16 + c][quad * 8];
      half8_t kf1 = *(const half8_t*)&Ks[tt * 16 + c][32 + quad * 8];
#pragma unroll
      for (int u = 0; u < 2; u++) {
        float4_t s = (float4_t){0.f, 0.f, 0.f, 0.f};
        s = __builtin_amdgcn_mfma_f32_16x16x32_f16(kf0, qf[u][0], s, 0, 0, 0);
        s = __builtin_amdgcn_mfma_f32_16x16x32_f16(kf1, qf[u][1], s, 0, 0, 0);
        S[u][tt] = s;
      }
    }

    // causal mask (only near-diagonal tiles)
    if (kk0 + 63 > wq0) {
#pragma unroll
      for (int u = 0; u < 2; u++)
#pragma unroll
        for (int tt = 0; tt < 4; tt++) {
          int base = kk0 + tt * 16 + quad * 4 - (wq0 + u * 16 + c);
#pragma unroll
          for (int r = 0; r < 4; r++)
            if (base + r > 0) S[u][tt][r] = -__builtin_inff();
        }
    }

    // online softmax (exp2 domain)
#pragma unroll
    for (int u = 0; u < 2; u++) {
      float4_t m4 = fmax4(fmax4(S[u][0], S[u][1]), fmax4(S[u][2], S[u][3]));
      float mloc = fmaxf(fmaxf(m4[0], m4[1]), fmaxf(m4[2], m4[3]));
      mloc = fmaxf(mloc, __shfl_xor(mloc, 16));
      mloc = fmaxf(mloc, __shfl_xor(mloc, 32));
      float mnew = fmaxf(mm[u], mloc);
      float al = exp2f(mm[u] - mnew);
      mm[u] = mnew;
#pragma unroll
      for (int tt = 0; tt < 4; tt++) {
#pragma unroll
        for (int r = 0; r < 4; r++) S[u][tt][r] = exp2f(S[u][tt][r] - mnew);
        half4_t pv;
#pragma unroll
        for (int r = 0; r < 4; r++) pv[r] = (half_t)S[u][tt][r];
        *(half4_t*)&Ps[w * 32 + u * 16 + c][tt * 16 + quad * 4] = pv;
      }
      float4_t s4 = S[u][0] + S[u][1] + S[u][2] + S[u][3];
      float ls = (s4[0] + s4[1]) + (s4[2] + s4[3]);
      ls += __shfl_xor(ls, 16);
      ls += __shfl_xor(ls, 32);
      ll[u] = ll[u] * al + ls;
      if (quad == 0) Ab[w * 32 + u * 16 + c] = al;   // broadcast alpha per q-row
    }

    // rescale O by per-row alpha
#pragma unroll
    for (int u = 0; u < 2; u++) {
      float4_t av = *(const float4_t*)&Ab[w * 32 + u * 16 + quad * 4];
#pragma unroll
      for (int dt = 0; dt < 4; dt++)
#pragma unroll
        for (int r = 0; r < 4; r++) o[u][dt][r] *= av[r];
    }

    // O += P V
    half8_t pf[2][2];
#pragma unroll
    for (int u = 0; u < 2; u++) {
      pf[u][0] = *(const half8_t*)&Ps[w * 32 + u * 16 + c][quad * 8];
      pf[u][1] = *(const half8_t*)&Ps[w * 32 + u * 16 + c][32 + quad * 8];
    }
#pragma unroll
    for (int dt = 0; dt < 4; dt++) {
      half8_t vf0 = *(const half8_t*)&Vs[dt * 16 + c][quad * 8];
      half8_t vf1 = *(const half8_t*)&Vs[dt * 16 + c][32 + quad * 8];
#pragma unroll
      for (int u = 0; u < 2; u++) {
        o[u][dt] = __builtin_amdgcn_mfma_f32_16x16x32_f16(pf[u][0], vf0, o[u][dt], 0, 0, 0);
        o[u][dt] = __builtin_amdgcn_mfma_f32_16x16x32_f16(pf[u][1], vf1, o[u][dt], 0, 0, 0);
      }
    }
  }

  // epilogue: broadcast l per q-row, normalize, store
#pragma unroll
  for (int u = 0; u < 2; u++)
    if (quad == 0) Ab[w * 32 + u * 16 + c] = ll[u];
#pragma unroll
  for (int u = 0; u < 2; u++) {
    float4_t lv = *(const float4_t*)&Ab[w * 32 + u * 16 + quad * 4];
#pragma unroll
    for (int r = 0; r < 4; r++) {
      float inv = 1.0f / lv[r];
      half_t* op = Oa + ((size_t)(b * L_ + wq0 + u * 16 + quad * 4 + r)) * (H_ * HD_)
                 + h * HD_ + c;
#pragma unroll
      for (int dt = 0; dt < 4; dt++)
        op[dt * 16] = (half_t)(o[u][dt][r] * inv);
    }
  }
}

// ---------------------------------------------------------------------------
extern "C" void kernel_launch(void* const* d_in, const int* in_sizes, int n_in,
                              void* d_out, int out_size, void* d_ws, size_t ws_size,
                              hipStream_t stream)
{
  const float* x  = (const float*)d_in[0];
  const float* Wq = (const float*)d_in[1];
  const float* Wk = (const float*)d_in[2];
  const float* Wv = (const float*)d_in[3];
  const float* Wo = (const float*)d_in[4];
  const float* qw = (const float*)d_in[5];
  const float* kw = (const float*)d_in[6];
  float* out = (float*)d_out;

  const size_t XN = (size_t)B_ * L_ * D_;          // 8M
  const size_t QN = (size_t)B_ * L_ * H_ * HD_;    // 8M
  const size_t KN = (size_t)B_ * L_ * HKV_ * HD_;  // 2M
  const size_t WQ = (size_t)D_ * H_ * HD_;         // 4M
  const size_t WK = (size_t)D_ * HKV_ * HD_;       // 1M

  half_t* p   = (half_t*)d_ws;
  half_t* xh  = p;  p += XN;   // reused as attn output
  half_t* Wqt = p;  p += WQ;
  half_t* Wkt = p;  p += WK;
  half_t* Wvt = p;  p += WK;
  half_t* Wot = p;  p += WQ;
  half_t* qh  = p;  p += QN;
  half_t* kh  = p;  p += KN;
  half_t* vh  = p;  p += KN;
  half_t* vt  = p;  p += KN;
  half_t* attn = xh;           // xh dead after qkv_gemm_h

  // 0) fused conversions + weight transposes
  prep_all<<<6656, 256, 0, stream>>>(x, Wq, Wk, Wv, Wo, xh, Wqt, Wkt, Wvt, Wot);

  // 1) QKV projections (fp16 MFMA)
  qkv_gemm_h<<<dim3(24, 32), 256, 0, stream>>>(xh, Wqt, Wkt, Wvt, qh, kh, vh);

  // 2) fused norm+RoPE (q,k) + V transpose
  postproc<<<32768 + 8192 + 512, 256, 0, stream>>>(qh, kh, vh, vt, qw, kw);

  // 3) MFMA flash attention (round-4 body + qb swizzle)
  flash_mfma2<<<dim3(L_ / 128, H_, B_), 256, 0, stream>>>(qh, kh, vt, attn);

  // 4) output projection (fp16 MFMA, fp32 out)
  out_gemm_h<<<dim3(16, 32), 256, 0, stream>>>(attn, Wot, out);
}